// Round 3
// baseline (1366.629 us; speedup 1.0000x reference)
//
#include <hip/hip_runtime.h>
#include <math.h>

// Problem constants
#define N_B 32
#define L_S 4096
#define D_M 768
#define H_N 12

// ws layout (float offsets). [0, ZERO_N) zeroed by one memset per call.
#define ZO_XBAR  0          // [32*12][768]
#define ZO_O     294912     // [32][768]
#define ZO_XA    319488     // [32][768]
#define ZO_H1P   344064     // [32][3072]
#define ZO_MACC  442368     // [32][768]
#define ZERO_N   466944
#define NZ_QK    466944     // [12][768] h-major
#define NZ_QB    476160     // [12] (pad 64)
#define NZ_ATTN  476224     // [32*12][4096]
#define NZ_Y     2049088    // [32][768]

// Canonical GCN 64-lane DPP sum (VALU-only, no DS pipe). Total lands in lane 63.
#define DPP_ADD(v, ctrl, rmask) \
  v += __int_as_float(__builtin_amdgcn_update_dpp(0, __float_as_int(v), ctrl, rmask, 0xf, false))

__device__ __forceinline__ float wave_sum63(float v) {
    DPP_ADD(v, 0x111, 0xf);  // row_shr:1
    DPP_ADD(v, 0x112, 0xf);  // row_shr:2
    DPP_ADD(v, 0x114, 0xf);  // row_shr:4
    DPP_ADD(v, 0x118, 0xf);  // row_shr:8  -> lane15 of each row16 = row sum
    DPP_ADD(v, 0x142, 0xa);  // row_bcast:15 -> rows 1,3
    DPP_ADD(v, 0x143, 0xc);  // row_bcast:31 -> rows 2,3; lane63 = total
    return v;
}

// ---------------------------------------------------------------------------
// prep: qh = 0.125*(probe@wq+bq) computed redundantly per block (wq L2-hot);
// qk[h][d] = qh_h . wk[d,h,:]; qb[h] = qh_h . bk_h. Grid (12 h, 3 dtile).
__global__ __launch_bounds__(256) void prep_kernel(
    const float* __restrict__ probe, const float* __restrict__ wq,
    const float* __restrict__ bq, const float* __restrict__ wk,
    const float* __restrict__ bk, float* __restrict__ qk,
    float* __restrict__ qb) {
    int h = blockIdx.x, dt = blockIdx.y, t = threadIdx.x;
    __shared__ float qh_s[768];
    float a0 = bq[t], a1 = bq[t + 256], a2 = bq[t + 512];
    for (int d = 0; d < 768; ++d) {
        float p = probe[d];
        const float* wr = wq + (size_t)d * 768;
        a0 += p * wr[t]; a1 += p * wr[t + 256]; a2 += p * wr[t + 512];
    }
    qh_s[t] = a0 * 0.125f; qh_s[t + 256] = a1 * 0.125f; qh_s[t + 512] = a2 * 0.125f;
    __syncthreads();
    int d = dt * 256 + t;
    const float4* wk4 = (const float4*)(wk + (size_t)d * 768 + h * 64);
    const float4* qh4 = (const float4*)(qh_s + h * 64);
    float acc = 0.f;
    #pragma unroll
    for (int e4 = 0; e4 < 16; ++e4) {
        float4 w = wk4[e4], q = qh4[e4];
        acc += w.x * q.x + w.y * q.y + w.z * q.z + w.w * q.w;
    }
    qk[h * 768 + d] = acc;
    if (dt == 0 && t < 64) {
        float v = qh_s[h * 64 + t] * bk[h * 64 + t];
        float s = wave_sum63(v);
        if (t == 63) qb[h] = s;
    }
}

// ---------------------------------------------------------------------------
// logits: wave per row-pair, fully coalesced x loads (lanes along d, 3
// dwordx4/row), qk from LDS as conflict-free b128, DPP reduction (VALU only).
// Grid 1024 blocks x 4 waves x 32 rows = 131072 rows.
__global__ __launch_bounds__(256, 4) void logits_kernel(
    const float* __restrict__ x, const float* __restrict__ qk,
    const float* __restrict__ qb, float* __restrict__ attn) {
    __shared__ float4 qk_s[2304];   // [h][192] float4
    __shared__ float qb_s[12];
    int t = threadIdx.x;
    const float4* qk4 = (const float4*)qk;
    for (int j = t; j < 2304; j += 256) qk_s[j] = qk4[j];
    if (t < 12) qb_s[t] = qb[t];
    __syncthreads();
    int w = t >> 6, lane = t & 63;
    size_t r0 = ((size_t)blockIdx.x * 4 + w) * 32;
    for (int rp = 0; rp < 16; ++rp) {
        size_t rA = r0 + rp * 2, rB = rA + 1;
        const float4* xA = (const float4*)(x + rA * 768);
        const float4* xB = (const float4*)(x + rB * 768);
        float4 a0 = xA[lane], a1 = xA[64 + lane], a2 = xA[128 + lane];
        float4 b0 = xB[lane], b1 = xB[64 + lane], b2 = xB[128 + lane];
        float pA[12], pB[12];
        #pragma unroll
        for (int h = 0; h < 12; ++h) {
            float4 q0 = qk_s[h * 192 + lane];
            float4 q1 = qk_s[h * 192 + 64 + lane];
            float4 q2 = qk_s[h * 192 + 128 + lane];
            pA[h] = a0.x * q0.x + a0.y * q0.y + a0.z * q0.z + a0.w * q0.w
                  + a1.x * q1.x + a1.y * q1.y + a1.z * q1.z + a1.w * q1.w
                  + a2.x * q2.x + a2.y * q2.y + a2.z * q2.z + a2.w * q2.w;
            pB[h] = b0.x * q0.x + b0.y * q0.y + b0.z * q0.z + b0.w * q0.w
                  + b1.x * q1.x + b1.y * q1.y + b1.z * q1.z + b1.w * q1.w
                  + b2.x * q2.x + b2.y * q2.y + b2.z * q2.z + b2.w * q2.w;
        }
        #pragma unroll
        for (int h = 0; h < 12; ++h) {
            pA[h] = wave_sum63(pA[h]);
            pB[h] = wave_sum63(pB[h]);
        }
        if (lane == 63) {
            int nA = (int)(rA >> 12), lA = (int)(rA & 4095);
            int nB = (int)(rB >> 12), lB = (int)(rB & 4095);
            #pragma unroll
            for (int h = 0; h < 12; ++h) {
                attn[((size_t)(nA * 12 + h)) * 4096 + lA] = pA[h] + qb_s[h];
                attn[((size_t)(nB * 12 + h)) * 4096 + lB] = pB[h] + qb_s[h];
            }
        }
    }
}

// ---------------------------------------------------------------------------
// softmax over L=4096, in place. One block per (n,h).
__global__ __launch_bounds__(256) void softmax_kernel(float* __restrict__ attn) {
    float* p = attn + (size_t)blockIdx.x * 4096;
    int tid = threadIdx.x;
    __shared__ float red[4];
    float v[16];
    #pragma unroll
    for (int k = 0; k < 16; ++k) v[k] = p[tid + 256 * k];
    float m = -1e30f;
    #pragma unroll
    for (int k = 0; k < 16; ++k) m = fmaxf(m, v[k]);
    #pragma unroll
    for (int off = 32; off > 0; off >>= 1) m = fmaxf(m, __shfl_xor(m, off));
    int wave = tid >> 6;
    if ((tid & 63) == 0) red[wave] = m;
    __syncthreads();
    m = fmaxf(fmaxf(red[0], red[1]), fmaxf(red[2], red[3]));
    float s = 0.f;
    #pragma unroll
    for (int k = 0; k < 16; ++k) { v[k] = expf(v[k] - m); s += v[k]; }
    #pragma unroll
    for (int off = 32; off > 0; off >>= 1) s += __shfl_xor(s, off);
    __syncthreads();
    if ((tid & 63) == 0) red[wave] = s;
    __syncthreads();
    s = red[0] + red[1] + red[2] + red[3];
    float inv = 1.f / s;
    #pragma unroll
    for (int k = 0; k < 16; ++k) p[tid + 256 * k] = v[k] * inv;
}

// ---------------------------------------------------------------------------
// xbar[n,h,d] = sum_l attn[n,h,l]*x[n,l,d]. Grid (8 lchunk, 3 dtile, 32 n).
// Wave w owns heads 3w..3w+2, stored at LDS slots l*16 + w*4 + c so the
// per-l weights are ONE broadcast ds_read_b128.
__global__ __launch_bounds__(256) void xbar_kernel(
    const float* __restrict__ x, const float* __restrict__ attn,
    float* __restrict__ xbar) {
    int lc = blockIdx.x, dt = blockIdx.y, n = blockIdx.z;
    __shared__ __align__(16) float at_s[512 * 16];
    int t = threadIdx.x;
    for (int idx = t; idx < 512 * 12; idx += 256) {
        int l = idx & 511, hh = idx >> 9;
        int wg = hh / 3, c = hh - wg * 3;
        at_s[l * 16 + wg * 4 + c] =
            attn[((size_t)(n * 12 + hh)) * 4096 + lc * 512 + l];
    }
    __syncthreads();
    int lane = t & 63, w = t >> 6;
    const float4* at4 = (const float4*)at_s;
    const float4* x4 = (const float4*)x;
    size_t base = ((size_t)n * 4096 + (size_t)lc * 512) * 192 + dt * 64 + lane;
    float4 a0 = {0, 0, 0, 0}, a1 = {0, 0, 0, 0}, a2 = {0, 0, 0, 0};
    for (int l = 0; l < 512; ++l) {
        float4 xv = x4[base + (size_t)l * 192];
        float4 aw = at4[l * 4 + w];   // broadcast: wave-uniform address
        a0.x += aw.x * xv.x; a0.y += aw.x * xv.y; a0.z += aw.x * xv.z; a0.w += aw.x * xv.w;
        a1.x += aw.y * xv.x; a1.y += aw.y * xv.y; a1.z += aw.y * xv.z; a1.w += aw.y * xv.w;
        a2.x += aw.z * xv.x; a2.y += aw.z * xv.y; a2.z += aw.z * xv.z; a2.w += aw.z * xv.w;
    }
    int h0 = w * 3;
    int d = dt * 256 + lane * 4;
    float* b0 = xbar + ((size_t)(n * 12 + h0)) * 768 + d;
    float* b1 = xbar + ((size_t)(n * 12 + h0 + 1)) * 768 + d;
    float* b2 = xbar + ((size_t)(n * 12 + h0 + 2)) * 768 + d;
    atomicAdd(b0 + 0, a0.x); atomicAdd(b0 + 1, a0.y); atomicAdd(b0 + 2, a0.z); atomicAdd(b0 + 3, a0.w);
    atomicAdd(b1 + 0, a1.x); atomicAdd(b1 + 1, a1.y); atomicAdd(b1 + 2, a1.z); atomicAdd(b1 + 3, a1.w);
    atomicAdd(b2 + 0, a2.x); atomicAdd(b2 + 1, a2.y); atomicAdd(b2 + 2, a2.z); atomicAdd(b2 + 3, a2.w);
}

// ---------------------------------------------------------------------------
// o[n][h*64+e] = sum_d xbar[n,h,d]*wv[d,h,e] (+bv at k0). Grid (12 h, 8 k).
__global__ __launch_bounds__(256) void oproj_kernel(
    const float* __restrict__ xbar, const float* __restrict__ wv,
    const float* __restrict__ bv, float* __restrict__ o) {
    int h = blockIdx.x, kk = blockIdx.y, t = threadIdx.x;
    int d0 = kk * 96;
    __shared__ __align__(16) float wv_s[96 * 64];
    __shared__ __align__(16) float xb_s[96 * 32];
    for (int i = t; i < 96 * 64; i += 256) {
        int d = i >> 6, e = i & 63;
        wv_s[i] = wv[(size_t)(d0 + d) * 768 + h * 64 + e];
    }
    for (int i = t; i < 96 * 32; i += 256) {
        int d = i >> 5, nn = i & 31;
        xb_s[i] = xbar[((size_t)(nn * 12 + h)) * 768 + d0 + d];
    }
    __syncthreads();
    int e = t & 63, ng = t >> 6;
    float acc[8] = {0, 0, 0, 0, 0, 0, 0, 0};
    for (int d = 0; d < 96; ++d) {
        float wvv = wv_s[d * 64 + e];
        const float4* xb4 = (const float4*)&xb_s[d * 32 + ng * 8];
        float4 p0 = xb4[0], p1 = xb4[1];
        acc[0] += p0.x * wvv; acc[1] += p0.y * wvv; acc[2] += p0.z * wvv; acc[3] += p0.w * wvv;
        acc[4] += p1.x * wvv; acc[5] += p1.y * wvv; acc[6] += p1.z * wvv; acc[7] += p1.w * wvv;
    }
    float bvv = (kk == 0) ? bv[h * 64 + e] : 0.f;
    #pragma unroll
    for (int k = 0; k < 8; ++k)
        atomicAdd(&o[(size_t)(ng * 8 + k) * 768 + h * 64 + e], acc[k] + bvv);
}

// xa[n][d] = sum_i o[n][i]*wo[i*768+d] (+bo at k0). Grid (3 dtile, 8 k).
__global__ __launch_bounds__(256) void xaproj_kernel(
    const float* __restrict__ o, const float* __restrict__ wo,
    const float* __restrict__ bo, float* __restrict__ xa) {
    int dt = blockIdx.x, kk = blockIdx.y, t = threadIdx.x;
    int i0 = kk * 96;
    __shared__ __align__(16) float o_s[96 * 32];
    for (int idx = t; idx < 96 * 32; idx += 256) {
        int i = idx >> 5, nn = idx & 31;
        o_s[idx] = o[(size_t)nn * 768 + i0 + i];
    }
    __syncthreads();
    int d = dt * 256 + t;
    float acc[32];
    #pragma unroll
    for (int nn = 0; nn < 32; ++nn) acc[nn] = 0.f;
    for (int i = 0; i < 96; ++i) {
        float w = wo[(size_t)(i0 + i) * 768 + d];
        const float4* o4 = (const float4*)&o_s[i * 32];
        #pragma unroll
        for (int q = 0; q < 8; ++q) {
            float4 f = o4[q];
            acc[q * 4 + 0] += f.x * w; acc[q * 4 + 1] += f.y * w;
            acc[q * 4 + 2] += f.z * w; acc[q * 4 + 3] += f.w * w;
        }
    }
    float bov = (kk == 0) ? bo[d] : 0.f;
    #pragma unroll
    for (int nn = 0; nn < 32; ++nn)
        atomicAdd(&xa[(size_t)nn * 768 + d], acc[nn] + bov);
}

// ---------------------------------------------------------------------------
// y = LayerNorm(xa). One block per n.
__global__ __launch_bounds__(256) void ln_kernel(
    const float* __restrict__ xa, const float* __restrict__ ln_scale,
    const float* __restrict__ ln_bias, float* __restrict__ y) {
    int n = blockIdx.x, tid = threadIdx.x;
    __shared__ float xs[768];
    __shared__ float red[4];
    for (int i = tid; i < 768; i += 256) xs[i] = xa[(size_t)n * 768 + i];
    __syncthreads();
    float lsum = 0.f;
    for (int i = tid; i < 768; i += 256) lsum += xs[i];
    #pragma unroll
    for (int off = 32; off > 0; off >>= 1) lsum += __shfl_xor(lsum, off);
    int wave = tid >> 6;
    if ((tid & 63) == 0) red[wave] = lsum;
    __syncthreads();
    float mu = (red[0] + red[1] + red[2] + red[3]) * (1.f / 768.f);
    __syncthreads();
    float lsq = 0.f;
    for (int i = tid; i < 768; i += 256) { float c = xs[i] - mu; lsq += c * c; }
    #pragma unroll
    for (int off = 32; off > 0; off >>= 1) lsq += __shfl_xor(lsq, off);
    if ((tid & 63) == 0) red[wave] = lsq;
    __syncthreads();
    float var = (red[0] + red[1] + red[2] + red[3]) * (1.f / 768.f);
    float rs = rsqrtf(var + 1e-6f);
    for (int i = tid; i < 768; i += 256)
        y[(size_t)n * 768 + i] = (xs[i] - mu) * rs * ln_scale[i] + ln_bias[i];
}

// ---------------------------------------------------------------------------
// h1pre[n][j] += sum_d y[n][d]*w1[d][j]. Grid (12 jtile, 16 k).
__global__ __launch_bounds__(256) void mlp1_kernel(
    const float* __restrict__ y, const float* __restrict__ w1,
    float* __restrict__ h1p) {
    int jt = blockIdx.x, kk = blockIdx.y, t = threadIdx.x;
    int d0 = kk * 48;
    __shared__ __align__(16) float y_s[48 * 32];
    for (int idx = t; idx < 48 * 32; idx += 256) {
        int d = idx >> 5, nn = idx & 31;
        y_s[idx] = y[(size_t)nn * 768 + d0 + d];
    }
    __syncthreads();
    int j = jt * 256 + t;
    float acc[32];
    #pragma unroll
    for (int nn = 0; nn < 32; ++nn) acc[nn] = 0.f;
    for (int d = 0; d < 48; ++d) {
        float w = w1[(size_t)(d0 + d) * 3072 + j];
        const float4* y4 = (const float4*)&y_s[d * 32];
        #pragma unroll
        for (int q = 0; q < 8; ++q) {
            float4 f = y4[q];
            acc[q * 4 + 0] += f.x * w; acc[q * 4 + 1] += f.y * w;
            acc[q * 4 + 2] += f.z * w; acc[q * 4 + 3] += f.w * w;
        }
    }
    #pragma unroll
    for (int nn = 0; nn < 32; ++nn)
        atomicAdd(&h1p[(size_t)nn * 3072 + j], acc[nn]);
}

// macc[n][d] += sum_j gelu(h1p+b1)[n][j]*w2[j][d]. Grid (3 dtile, 64 k).
// gelu fused into the staging load.
__global__ __launch_bounds__(256) void mlp2_kernel(
    const float* __restrict__ h1p, const float* __restrict__ b1,
    const float* __restrict__ w2, float* __restrict__ macc) {
    int dt = blockIdx.x, kk = blockIdx.y, t = threadIdx.x;
    int j0 = kk * 48;
    __shared__ __align__(16) float h_s[48 * 32];
    for (int idx = t; idx < 48 * 32; idx += 256) {
        int j = idx >> 5, nn = idx & 31;
        float tv = h1p[(size_t)nn * 3072 + j0 + j] + b1[j0 + j];
        h_s[idx] = 0.5f * tv * (1.f + tanhf(0.7978845608028654f *
                       (tv + 0.044715f * tv * tv * tv)));
    }
    __syncthreads();
    int d = dt * 256 + t;
    float acc[32];
    #pragma unroll
    for (int nn = 0; nn < 32; ++nn) acc[nn] = 0.f;
    for (int j = 0; j < 48; ++j) {
        float w = w2[(size_t)(j0 + j) * 768 + d];
        const float4* h4 = (const float4*)&h_s[j * 32];
        #pragma unroll
        for (int q = 0; q < 8; ++q) {
            float4 f = h4[q];
            acc[q * 4 + 0] += f.x * w; acc[q * 4 + 1] += f.y * w;
            acc[q * 4 + 2] += f.z * w; acc[q * 4 + 3] += f.w * w;
        }
    }
    #pragma unroll
    for (int nn = 0; nn < 32; ++nn)
        atomicAdd(&macc[(size_t)nn * 768 + d], acc[nn]);
}

// out = xa + b2 + macc. Grid 32 n.
__global__ __launch_bounds__(256) void final_kernel(
    const float* __restrict__ xa, const float* __restrict__ b2,
    const float* __restrict__ macc, float* __restrict__ out) {
    int n = blockIdx.x, t = threadIdx.x;
    for (int i = t; i < 768; i += 256)
        out[(size_t)n * 768 + i] = xa[(size_t)n * 768 + i] + b2[i] + macc[(size_t)n * 768 + i];
}

// ---------------------------------------------------------------------------
extern "C" void kernel_launch(void* const* d_in, const int* in_sizes, int n_in,
                              void* d_out, int out_size, void* d_ws, size_t ws_size,
                              hipStream_t stream) {
    const float* x        = (const float*)d_in[0];
    const float* probe    = (const float*)d_in[1];
    const float* wq       = (const float*)d_in[2];
    const float* bq       = (const float*)d_in[3];
    const float* wk       = (const float*)d_in[4];
    const float* bk       = (const float*)d_in[5];
    const float* wv       = (const float*)d_in[6];
    const float* bv       = (const float*)d_in[7];
    const float* wo       = (const float*)d_in[8];
    const float* bo       = (const float*)d_in[9];
    const float* ln_scale = (const float*)d_in[10];
    const float* ln_bias  = (const float*)d_in[11];
    const float* w1       = (const float*)d_in[12];
    const float* b1       = (const float*)d_in[13];
    const float* w2       = (const float*)d_in[14];
    const float* b2       = (const float*)d_in[15];
    float* out = (float*)d_out;
    float* ws  = (float*)d_ws;

    float* xbar = ws + ZO_XBAR;
    float* o    = ws + ZO_O;
    float* xa   = ws + ZO_XA;
    float* h1p  = ws + ZO_H1P;
    float* macc = ws + ZO_MACC;
    float* qk   = ws + NZ_QK;
    float* qb   = ws + NZ_QB;
    float* attn = ws + NZ_ATTN;
    float* y    = ws + NZ_Y;

    hipMemsetAsync(ws, 0, (size_t)ZERO_N * sizeof(float), stream);
    prep_kernel<<<dim3(12, 3), 256, 0, stream>>>(probe, wq, bq, wk, bk, qk, qb);
    logits_kernel<<<1024, 256, 0, stream>>>(x, qk, qb, attn);
    softmax_kernel<<<N_B * H_N, 256, 0, stream>>>(attn);
    xbar_kernel<<<dim3(8, 3, 32), 256, 0, stream>>>(x, attn, xbar);
    oproj_kernel<<<dim3(12, 8), 256, 0, stream>>>(xbar, wv, bv, o);
    xaproj_kernel<<<dim3(3, 8), 256, 0, stream>>>(o, wo, bo, xa);
    ln_kernel<<<N_B, 256, 0, stream>>>(xa, ln_scale, ln_bias, y);
    mlp1_kernel<<<dim3(12, 16), 256, 0, stream>>>(y, w1, h1p);
    mlp2_kernel<<<dim3(3, 64), 256, 0, stream>>>(h1p, b1, w2, macc);
    final_kernel<<<N_B, 256, 0, stream>>>(xa, b2, macc, out);
}